// Round 5
// baseline (2112.557 us; speedup 1.0000x reference)
//
#include <hip/hip_runtime.h>
#include <math.h>

#define T_STEPS 50
#define NT 1024

// workspace layout (float offsets)
#define WS_FC1T 0          // 1600*256 = 409600  : fc1_w transposed [k][j]
#define WS_W2F  409600     // 32*9*64*4 = 73728  : folded conv2, tap-quad-major [ic][q][oc][4]
#define WS_W1F  483328     // 36*64    = 2304    : folded conv1 [j][oc*2+ic]
#define WS_TOTAL 485632

// LDS layout (float offsets)
#define L_XT    0          // 2048
#define L_SPK1  2048       // 32 planes, stride 228 = 7296
#define L_RED   9344       // 8*1600 = 12800
#define L_WOUT  22144      // 2816
#define L_LIST  24960      // 1600 (ints)
#define L_FLAG  26560      // 448
#define L_CNT   27008      // 16 (pad)
#define L_VC1   27024      // 6272 : conv1 membrane, [py*14+px]*32 + oc
#define L_VC2   33296      // 1600
#define L_BN2   34896      // 192 : s2 | sh2 | b2
#define L_IPART2 35088     // 4096 : fc1 partials, 16 wave-groups x 256
#define L_FCP   39184      // 768 : alpha | rho | beta_a (256 each)
#define L_FCS   39952      // 768 : vfc | afc | spf (256 each)
#define L_TOTALF 40720     // 162880 B <= 163840 (160 KiB)
#define SMEM_BYTES (L_TOTALF * 4)

__global__ void prep_kernel(const float* __restrict__ conv1_w,
                            const float* __restrict__ conv2_w,
                            const float* __restrict__ fc1_w,
                            float* __restrict__ ws) {
  int i = blockIdx.x * blockDim.x + threadIdx.x;
  if (i < 409600) {
    int k = i >> 8, j = i & 255;
    ws[WS_FC1T + i] = fc1_w[j * 1600 + k];
  } else if (i < 409600 + 73728) {
    // tap-quad-major layout: index = ((ic*9 + q)*64 + oc)*4 + r, tap jj = 4q + r.
    int i2 = i - 409600;
    int r  = i2 & 3;
    int t2 = i2 >> 2;
    int oc = t2 & 63;
    int t3 = t2 >> 6;      // ic*9 + q
    int q  = t3 % 9;
    int ic = t3 / 9;
    int jj = q * 4 + r, u = jj / 6, v = jj % 6;
    float s = 0.f;
    for (int dy = 0; dy < 2; ++dy) {
      int ky = u - dy; if (ky < 0 || ky > 4) continue;
      for (int dx = 0; dx < 2; ++dx) {
        int kx = v - dx; if (kx < 0 || kx > 4) continue;
        s += conv2_w[((oc * 32 + ic) * 5 + ky) * 5 + kx];
      }
    }
    ws[WS_W2F + i2] = 0.25f * s;
  } else if (i < WS_TOTAL) {
    int i3 = i - 483328;
    int jj = i3 >> 6, l = i3 & 63, oc = l >> 1, ic = l & 1, u = jj / 6, v = jj % 6;
    float s = 0.f;
    for (int dy = 0; dy < 2; ++dy) {
      int ky = u - dy; if (ky < 0 || ky > 4) continue;
      for (int dx = 0; dx < 2; ++dx) {
        int kx = v - dx; if (kx < 0 || kx > 4) continue;
        s += conv1_w[((oc * 2 + ic) * 5 + ky) * 5 + kx];
      }
    }
    ws[WS_W1F + i3] = 0.25f * s;
  }
}

// conv2 half-wave body: rows iy in [IYLO,IYHI], outputs py in [PYLO,PYHI].
#define CONV2_BODY(IYLO, IYHI, PYLO, PYHI)                                   \
  for (int ib = 0; ib < 4; ++ib) {                                           \
    const int ic = g + 8 * ib;                                               \
    const float* fl = &sm[L_FLAG + ic * 14];                                 \
    float fsum = 0.f;                                                        \
    _Pragma("unroll")                                                        \
    for (int iy = IYLO; iy <= IYHI; ++iy) fsum += fl[iy];                    \
    if (fsum != 0.f) {                                                       \
      float w[36];                                                           \
      {                                                                      \
        const float4* wp = ((const float4*)w2f) + (ic * 9) * 64 + lane;      \
        _Pragma("unroll")                                                    \
        for (int q = 0; q < 9; ++q) {                                        \
          float4 f = wp[q * 64];                                             \
          w[4*q] = f.x; w[4*q+1] = f.y; w[4*q+2] = f.z; w[4*q+3] = f.w;      \
        }                                                                    \
      }                                                                      \
      const float* srow = &sm[L_SPK1 + ic * 228];                            \
      _Pragma("unroll")                                                      \
      for (int iy = IYLO; iy <= IYHI; ++iy) {                                \
        if (fl[iy] != 0.f) {                                                 \
          float row[16];                                                     \
          const float4* rp = (const float4*)&srow[iy * 16];                  \
          _Pragma("unroll")                                                  \
          for (int q = 0; q < 4; ++q) {                                      \
            float4 f = rp[q];                                                \
            row[4*q] = f.x; row[4*q+1] = f.y; row[4*q+2] = f.z; row[4*q+3] = f.w; \
          }                                                                  \
          _Pragma("unroll")                                                  \
          for (int py = PYLO; py <= PYHI; ++py) {                            \
            const int u = iy - 2 * py;                                       \
            if (u >= 0 && u <= 5) {                                          \
              _Pragma("unroll")                                              \
              for (int v = 0; v < 6; ++v) {                                  \
                float wv = w[u * 6 + v];                                     \
                _Pragma("unroll")                                            \
                for (int px = 0; px < 5; ++px)                               \
                  acc[(py - PYLO) * 5 + px] += row[2*px + v] * wv;           \
              }                                                              \
            }                                                                \
          }                                                                  \
        }                                                                    \
      }                                                                      \
    }                                                                        \
  }

// block = 1024 (16 waves), LDS 162.9KB -> 1 WG/CU = 4 waves/SIMD.
// CRITICAL: amdgpu_waves_per_eu(4,4) with explicit MAX=4. Round-2's
// __launch_bounds__(1024,4) let the allocator over-target 8 waves/EU and pick
// VGPR=64, which spilled 1.38 GB/dispatch of scratch (216KB/block/step) and
// made the run 2.6x slower. max=4 pins the cap at 512/4 = 128 VGPRs, which
// fits the phase-3 live set (~115 regs). If VGPR_Count reads 64 again, this
// knob is broken and the 16-wave axis is dead.
__global__ __attribute__((amdgpu_flat_work_group_size(1024, 1024),
                          amdgpu_waves_per_eu(4, 4)))
void snn_kernel(
    const float* __restrict__ x,
    const float* __restrict__ bn1_gamma, const float* __restrict__ bn1_beta,
    const float* __restrict__ bn1_mean,  const float* __restrict__ bn1_var,
    const float* __restrict__ bn2_gamma, const float* __restrict__ bn2_beta,
    const float* __restrict__ bn2_mean,  const float* __restrict__ bn2_var,
    const float* __restrict__ beta_c1_raw, const float* __restrict__ beta_c2_raw,
    const float* __restrict__ alpha_raw, const float* __restrict__ rho_raw,
    const float* __restrict__ beta_a_p,  const float* __restrict__ fc_out_w,
    const float* __restrict__ beta_out_p,
    const float* __restrict__ ws, float* __restrict__ out)
{
  extern __shared__ float sm[];
  int* listI = (int*)&sm[L_LIST];
  int* cntI  = (int*)&sm[L_CNT];
  const int tid = threadIdx.x, wave = tid >> 6, lane = tid & 63;
  const int b = blockIdx.x;

  // one-time LDS staging + state zero-init
  for (int i = tid; i < 2816; i += NT) sm[L_WOUT + i] = fc_out_w[i];
  for (int i = tid; i < 6272; i += NT) sm[L_VC1 + i] = 0.f;
  for (int i = tid; i < 1600; i += NT) sm[L_VC2 + i] = 0.f;
  if (tid < 256) {
    // fc params+state in LDS: only wave 0 touches them after init, keeps them
    // out of the per-wave register budget.
    sm[L_FCP + tid]       = 1.f / (1.f + expf(-alpha_raw[tid]));
    sm[L_FCP + 256 + tid] = 1.f / (1.f + expf(-rho_raw[tid]));
    sm[L_FCP + 512 + tid] = beta_a_p[tid];
    sm[L_FCS + tid] = 0.f;
    sm[L_FCS + 256 + tid] = 0.f;
    sm[L_FCS + 512 + tid] = 0.f;
  }
  if (tid < 64) {
    float s2 = bn2_gamma[tid] / sqrtf(bn2_var[tid] + 1e-5f);
    sm[L_BN2 + tid]       = s2;
    sm[L_BN2 + 64 + tid]  = bn2_beta[tid] - bn2_mean[tid] * s2;
    sm[L_BN2 + 128 + tid] = 1.f / (1.f + expf(-beta_c2_raw[tid]));
  }

  // conv1 lane mapping: lane = oc*2 + ic
  const int oc1 = lane >> 1, ic1 = lane & 1;
  const float s1v  = bn1_gamma[oc1] / sqrtf(bn1_var[oc1] + 1e-5f);
  const float sh1v = bn1_beta[oc1] - bn1_mean[oc1] * s1v;
  const float b1v  = 1.f / (1.f + expf(-beta_c1_raw[oc1]));
  const float beta_o = 1.f / (1.f + expf(-beta_out_p[0]));

  // conv1 weights: persistent in registers (36 regs; used by waves 0-13)
  float w1r[36];
  #pragma unroll
  for (int j = 0; j < 36; ++j) w1r[j] = ws[WS_W1F + j * 64 + lane];

  float v_out = 0.f, o_sum = 0.f;  // wave0, lane<11

  const float* xbase = x + (size_t)b * T_STEPS * 2048;
  const float* w2f  = ws + WS_W2F;
  const float* fc1T = ws + WS_FC1T;

  float2 xpre = ((const float2*)xbase)[tid];   // prefetch t=0 (1024 thr x 8B)

  __syncthreads();

  for (int t = 0; t < T_STEPS; ++t) {
    // ---- phase 1: commit prefetched x_t to LDS ----
    ((float2*)&sm[L_XT])[tid] = xpre;
    __syncthreads();                                     // barrier A
    {
      int tn = (t + 1 < T_STEPS) ? t + 1 : t;
      xpre = ((const float2*)(xbase + tn * 2048))[tid];  // prefetch t+1 (latency hidden)
    }

    // ---- phase 2: conv1 (folded 6x6, stride2) + BN + LIF; one row per wave ----
    if (wave < 14) {
      const int py = wave;
      float acc[14];
      #pragma unroll
      for (int p = 0; p < 14; ++p) acc[p] = 0.f;
      const float* xr = &sm[L_XT + ic1 * 1024 + py * 64];
      #pragma unroll
      for (int r = 0; r < 6; ++r) {
        float row[32];
        const float4* rp = (const float4*)&xr[r * 32];
        #pragma unroll
        for (int q = 0; q < 8; ++q) {
          float4 f = rp[q];
          row[4*q] = f.x; row[4*q+1] = f.y; row[4*q+2] = f.z; row[4*q+3] = f.w;
        }
        #pragma unroll
        for (int v = 0; v < 6; ++v) {
          float wv = w1r[r * 6 + v];
          #pragma unroll
          for (int px = 0; px < 14; ++px) acc[px] += row[2*px + v] * wv;
        }
      }
      #pragma unroll
      for (int px = 0; px < 14; ++px) acc[px] += __shfl_xor(acc[px], 1);
      if (ic1 == 0) {
        float flag = 0.f;
        #pragma unroll
        for (int px = 0; px < 14; ++px) {
          float c = acc[px] * s1v + sh1v;
          const int vidx = L_VC1 + (py * 14 + px) * 32 + oc1;
          float vold = sm[vidx];
          float v = b1v * vold + (1.f - b1v) * c;
          float s = (v > 1.f) ? 1.f : 0.f;
          sm[vidx] = v * (1.f - s);
          sm[L_SPK1 + oc1 * 228 + py * 16 + px] = s;
          flag += s;
        }
        sm[L_FLAG + oc1 * 14 + py] = flag;
      }
    }
    if (tid == 0) *cntI = 0;
    __syncthreads();                                     // barrier B

    // ---- phase 3: conv2; wave=(g,h): g -> 4 ic planes, h -> py half ----
    {
      const int g = wave & 7, h = wave >> 3;
      float acc[15];
      #pragma unroll
      for (int p = 0; p < 15; ++p) acc[p] = 0.f;
      if (h == 0) {
        CONV2_BODY(0, 7, 0, 2)          // py 0..2 (15 outputs), rows iy 0..7
      } else {
        CONV2_BODY(6, 13, 3, 4)         // py 3..4 (10 outputs), rows iy 6..13
      }
      // disjoint slices of RED[g]: h=0 -> p 0..14, h=1 -> p 15..24
      if (h == 0) {
        #pragma unroll
        for (int p = 0; p < 15; ++p) sm[L_RED + g * 1600 + lane * 25 + p] = acc[p];
      } else {
        #pragma unroll
        for (int p = 0; p < 10; ++p) sm[L_RED + g * 1600 + lane * 25 + 15 + p] = acc[p];
      }
    }
    __syncthreads();                                     // barrier C

    // ---- phase 4: reduce + BN + LIF -> spike list (ballot compaction) ----
    {
      #pragma unroll
      for (int k = 0; k < 2; ++k) {
        int n = tid + NT * k;
        float s = 0.f;
        if (n < 1600) {
          float ssum = 0.f;
          #pragma unroll
          for (int wv = 0; wv < 8; ++wv) ssum += sm[L_RED + wv * 1600 + n];
          int oc = n / 25;
          float c2 = ssum * sm[L_BN2 + oc] + sm[L_BN2 + 64 + oc];
          float b2 = sm[L_BN2 + 128 + oc];
          const int vidx = L_VC2 + n;
          float vold = sm[vidx];
          float v = b2 * vold + (1.f - b2) * c2;
          s = (v > 1.f) ? 1.f : 0.f;
          sm[vidx] = v * (1.f - s);
        }
        unsigned long long mask = __ballot(s > 0.f);
        if (mask) {
          int base = 0;
          if (lane == 0) base = atomicAdd(cntI, __popcll(mask));
          base = __shfl(base, 0);
          if (s > 0.f) {
            int pos = __popcll(mask & ((1ull << lane) - 1ull));
            listI[base + pos] = n;
          }
        }
      }
    }
    __syncthreads();                                     // barrier D

    // ---- phase 5: fc1 = sparse gather, float4/lane, 16-way wave split, 4 accumulators ----
    {
      const int j4 = lane;           // float4 column index
      const int h  = wave;
      const int nn = *cntI;
      const float4* fc4 = (const float4*)fc1T;
      float4 a0 = {0.f,0.f,0.f,0.f}, a1 = {0.f,0.f,0.f,0.f};
      float4 a2 = {0.f,0.f,0.f,0.f}, a3 = {0.f,0.f,0.f,0.f};
      int i = h;
      for (; i + 48 < nn; i += 64) {
        int k0 = listI[i], k1 = listI[i + 16], k2 = listI[i + 32], k3 = listI[i + 48];
        float4 f0 = fc4[k0 * 64 + j4];
        float4 f1 = fc4[k1 * 64 + j4];
        float4 f2 = fc4[k2 * 64 + j4];
        float4 f3 = fc4[k3 * 64 + j4];
        a0.x += f0.x; a0.y += f0.y; a0.z += f0.z; a0.w += f0.w;
        a1.x += f1.x; a1.y += f1.y; a1.z += f1.z; a1.w += f1.w;
        a2.x += f2.x; a2.y += f2.y; a2.z += f2.z; a2.w += f2.w;
        a3.x += f3.x; a3.y += f3.y; a3.z += f3.z; a3.w += f3.w;
      }
      for (; i < nn; i += 16) {
        int k = listI[i];
        float4 f = fc4[k * 64 + j4];
        a0.x += f.x; a0.y += f.y; a0.z += f.z; a0.w += f.w;
      }
      a0.x += a1.x + a2.x + a3.x;
      a0.y += a1.y + a2.y + a3.y;
      a0.z += a1.z + a2.z + a3.z;
      a0.w += a1.w + a2.w + a3.w;
      ((float4*)&sm[L_IPART2])[h * 64 + j4] = a0;
    }
    __syncthreads();                                     // barrier E

    // ---- phases 6-8 (wave 0 only): fc adaptive LIF, fc_out, output integrator ----
    // Neuron ownership j = lane + 64k (stride-1 accesses, conflict-free).
    // No trailing barrier: next step's barrier A orders IPART2/LIST reuse.
    if (wave == 0) {
      float s[4];
      #pragma unroll
      for (int k = 0; k < 4; ++k) {
        int j = lane + 64 * k;
        float I = 0.f;
        #pragma unroll
        for (int h2 = 0; h2 < 16; ++h2) I += sm[L_IPART2 + h2 * 256 + j];
        float al = sm[L_FCP + j], rh = sm[L_FCP + 256 + j], ba = sm[L_FCP + 512 + j];
        float vf = sm[L_FCS + j], af = sm[L_FCS + 256 + j], sp0 = sm[L_FCS + 512 + j];
        af = rh * af + (1.f - rh) * sp0;
        float v = al * vf + (1.f - al) * I;
        float sp = (v > 1.f + ba * af) ? 1.f : 0.f;
        sm[L_FCS + j] = v * (1.f - sp);
        sm[L_FCS + 256 + j] = af;
        sm[L_FCS + 512 + j] = sp;
        s[k] = sp;
      }
      float p[11];
      #pragma unroll
      for (int o = 0; o < 11; ++o) {
        p[o] = 0.f;
        #pragma unroll
        for (int k = 0; k < 4; ++k)
          p[o] += s[k] * sm[L_WOUT + o * 256 + lane + 64 * k];
      }
      #pragma unroll
      for (int m = 1; m < 64; m <<= 1)
        #pragma unroll
        for (int o = 0; o < 11; ++o) p[o] += __shfl_xor(p[o], m);
      float Isel = p[0];
      #pragma unroll
      for (int o = 1; o < 11; ++o) Isel = (lane == o) ? p[o] : Isel;
      if (lane < 11) {
        v_out = beta_o * v_out + (1.f - beta_o) * Isel;
        o_sum += v_out;
      }
    }
  }

  if (wave == 0 && lane < 11) out[b * 11 + lane] = o_sum * (1.f / T_STEPS);
}

extern "C" void kernel_launch(void* const* d_in, const int* in_sizes, int n_in,
                              void* d_out, int out_size, void* d_ws, size_t ws_size,
                              hipStream_t stream) {
  const float* x            = (const float*)d_in[0];
  const float* conv1_w      = (const float*)d_in[1];
  const float* bn1_gamma    = (const float*)d_in[2];
  const float* bn1_beta     = (const float*)d_in[3];
  const float* bn1_mean     = (const float*)d_in[4];
  const float* bn1_var      = (const float*)d_in[5];
  const float* conv2_w      = (const float*)d_in[6];
  const float* bn2_gamma    = (const float*)d_in[7];
  const float* bn2_beta     = (const float*)d_in[8];
  const float* bn2_mean     = (const float*)d_in[9];
  const float* bn2_var      = (const float*)d_in[10];
  const float* beta_c1_raw  = (const float*)d_in[11];
  const float* beta_c2_raw  = (const float*)d_in[12];
  const float* fc1_w        = (const float*)d_in[13];
  const float* alpha_raw    = (const float*)d_in[14];
  const float* rho_raw      = (const float*)d_in[15];
  const float* beta_a_p     = (const float*)d_in[16];
  const float* fc_out_w     = (const float*)d_in[17];
  const float* beta_out_p   = (const float*)d_in[18];
  float* ws  = (float*)d_ws;
  float* outp = (float*)d_out;

  (void)in_sizes; (void)n_in; (void)out_size; (void)ws_size;

  hipFuncSetAttribute((const void*)snn_kernel,
                      hipFuncAttributeMaxDynamicSharedMemorySize, SMEM_BYTES);

  prep_kernel<<<dim3((WS_TOTAL + 255) / 256), dim3(256), 0, stream>>>(
      conv1_w, conv2_w, fc1_w, ws);

  snn_kernel<<<dim3(128), dim3(NT), SMEM_BYTES, stream>>>(
      x, bn1_gamma, bn1_beta, bn1_mean, bn1_var,
      bn2_gamma, bn2_beta, bn2_mean, bn2_var,
      beta_c1_raw, beta_c2_raw, alpha_raw, rho_raw, beta_a_p,
      fc_out_w, beta_out_p, ws, outp);
}

// Round 6
// 863.108 us; speedup vs baseline: 2.4476x; 2.4476x over previous
//
#include <hip/hip_runtime.h>
#include <math.h>

#define T_STEPS 50
#define NT 768

// workspace layout (float offsets)
#define WS_FC1T 0          // 1600*256 = 409600 : fc1_w transposed [k][j]
#define WS_W2F  409600     // 32*3*3*256 = 73728 : folded conv2, u-pair layout
                           //   ((ic*3+h)*3+q)*256 + oc*4 + r ; tap j=4q+r in [0,12),
                           //   u = 2h + (j>=6), v = j%6
#define WS_W1F  483328     // 36*64 = 2304 : folded conv1 [j][oc*2+ic]
#define WS_WOUTP 485632    // 2816 : fc_out packed [(o*64+lane)*4+k] = fc_out[o*256+k*64+lane]
#define WS_TOTAL 488448

// LDS layout (float offsets). Aliasing is load-bearing:
//  - P region holds conv2 RED buffers 8-11 (phases 3-4) AND the x_t tile XT
//    [0,2080) (phases 1-2, ic-stride 1040 to kill 2-way bank conflicts).
//  - IPART2 (fc1 partials, phases 5-6) aliases RED[0..3072) (dead after barrier D).
//  Safety: barriers B/C/D/E separate every writer from the aliased reader, and
//  wave0's phase 6 finishes before any wave passes barrier A (all waves wait).
#define L_P     0          // 6400 : RED bufs 8-11 ; XT = P[0..2080), stride 1040
#define L_SPK1  6400       // 7296 : 32 planes, stride 228
#define L_RED   13696      // 12800 : RED bufs 0-7
#define L_IPART2 L_RED     // 3072 alias
#define L_LIST  26496      // 1600 (ints)
#define L_FLAG  28096      // 448
#define L_CNT   28544      // 16
#define L_VC1   28560      // 6272 : conv1 membrane, [py*14+px]*32 + oc
#define L_VC2   34832      // 1600
#define L_BN2   36432      // 192 : s2 | sh2 | b2
#define L_FCP   36624      // 768 : alpha | rho | beta_a
#define L_FCS   37392      // 768 : vfc | afc | spf
#define L_TOTALF 38160     // 152640 B <= 163840
#define SMEM_BYTES (L_TOTALF * 4)

__global__ void prep_kernel(const float* __restrict__ conv1_w,
                            const float* __restrict__ conv2_w,
                            const float* __restrict__ fc1_w,
                            const float* __restrict__ fc_out_w,
                            float* __restrict__ ws) {
  int i = blockIdx.x * blockDim.x + threadIdx.x;
  if (i < 409600) {
    int k = i >> 8, j = i & 255;
    ws[WS_FC1T + i] = fc1_w[j * 1600 + k];
  } else if (i < 483328) {
    // u-pair conv2 layout: i2 = (((ic*3+h)*3+q)*64 + oc)*4 + r
    int i2 = i - 409600;
    int r  = i2 & 3;
    int s_ = i2 >> 2;
    int oc = s_ & 63;
    int m  = s_ >> 6;        // (ic*3+h)*3+q
    int q  = m % 3;
    int hh = (m / 3) % 3;
    int ic = m / 9;
    int j  = q * 4 + r;      // 0..11
    int u  = 2 * hh + (j >= 6 ? 1 : 0);
    int v  = (j >= 6) ? j - 6 : j;
    float s = 0.f;
    for (int dy = 0; dy < 2; ++dy) {
      int ky = u - dy; if (ky < 0 || ky > 4) continue;
      for (int dx = 0; dx < 2; ++dx) {
        int kx = v - dx; if (kx < 0 || kx > 4) continue;
        s += conv2_w[((oc * 32 + ic) * 5 + ky) * 5 + kx];
      }
    }
    ws[WS_W2F + i2] = 0.25f * s;
  } else if (i < 485632) {
    int i3 = i - 483328;
    int jj = i3 >> 6, l = i3 & 63, oc = l >> 1, ic = l & 1, u = jj / 6, v = jj % 6;
    float s = 0.f;
    for (int dy = 0; dy < 2; ++dy) {
      int ky = u - dy; if (ky < 0 || ky > 4) continue;
      for (int dx = 0; dx < 2; ++dx) {
        int kx = v - dx; if (kx < 0 || kx > 4) continue;
        s += conv1_w[((oc * 2 + ic) * 5 + ky) * 5 + kx];
      }
    }
    ws[WS_W1F + i3] = 0.25f * s;
  } else if (i < WS_TOTAL) {
    // fc_out packed for per-lane float4 loads in phase 6
    int i4 = i - 485632;
    int k  = i4 & 3;
    int s_ = i4 >> 2;
    int ln = s_ & 63;
    int o  = s_ >> 6;
    ws[WS_WOUTP + i4] = fc_out_w[o * 256 + k * 64 + ln];
  }
}

// block = 768 (12 waves), LDS 149KB -> 1 WG/CU = 3 waves/SIMD.
// VGPR strategy: the allocator empirically picks HALF the residency cap
// implied by launch_bounds arg2 ((512,2)->128, (1024,4)->64 w/ 1.4GB spill).
// (768,2) therefore aims 4 waves/EU -> 128 VGPRs = the proven no-spill point,
// while the dynamic-LDS limit (1 WG) gives 12 resident waves. If VGPR_Count
// reads 64/85 with GB-scale FETCH, this axis is dead.
__global__ __launch_bounds__(NT, 2) void snn_kernel(
    const float* __restrict__ x,
    const float* __restrict__ bn1_gamma, const float* __restrict__ bn1_beta,
    const float* __restrict__ bn1_mean,  const float* __restrict__ bn1_var,
    const float* __restrict__ bn2_gamma, const float* __restrict__ bn2_beta,
    const float* __restrict__ bn2_mean,  const float* __restrict__ bn2_var,
    const float* __restrict__ beta_c1_raw, const float* __restrict__ beta_c2_raw,
    const float* __restrict__ alpha_raw, const float* __restrict__ rho_raw,
    const float* __restrict__ beta_a_p,  const float* __restrict__ fc_out_w,
    const float* __restrict__ beta_out_p,
    const float* __restrict__ ws, float* __restrict__ out)
{
  extern __shared__ float sm[];
  int* listI = (int*)&sm[L_LIST];
  int* cntI  = (int*)&sm[L_CNT];
  const int tid = threadIdx.x, wave = tid >> 6, lane = tid & 63;
  const int b = blockIdx.x;

  // one-time state zero-init + param staging
  for (int i = tid; i < 6272; i += NT) sm[L_VC1 + i] = 0.f;
  for (int i = tid; i < 1600; i += NT) sm[L_VC2 + i] = 0.f;
  if (tid < 256) {
    sm[L_FCP + tid]       = 1.f / (1.f + expf(-alpha_raw[tid]));
    sm[L_FCP + 256 + tid] = 1.f / (1.f + expf(-rho_raw[tid]));
    sm[L_FCP + 512 + tid] = beta_a_p[tid];
    sm[L_FCS + tid] = 0.f;
    sm[L_FCS + 256 + tid] = 0.f;
    sm[L_FCS + 512 + tid] = 0.f;
  }
  if (tid < 64) {
    float s2 = bn2_gamma[tid] / sqrtf(bn2_var[tid] + 1e-5f);
    sm[L_BN2 + tid]       = s2;
    sm[L_BN2 + 64 + tid]  = bn2_beta[tid] - bn2_mean[tid] * s2;
    sm[L_BN2 + 128 + tid] = 1.f / (1.f + expf(-beta_c2_raw[tid]));
  }

  // conv1 lane mapping: lane = oc*2 + ic
  const int oc1 = lane >> 1, ic1 = lane & 1;
  const float s1v  = bn1_gamma[oc1] / sqrtf(bn1_var[oc1] + 1e-5f);
  const float sh1v = bn1_beta[oc1] - bn1_mean[oc1] * s1v;
  const float b1v  = 1.f / (1.f + expf(-beta_c1_raw[oc1]));
  const float beta_o = 1.f / (1.f + expf(-beta_out_p[0]));

  // conv1 weights: persistent in registers (36 regs)
  float w1r[36];
  #pragma unroll
  for (int j = 0; j < 36; ++j) w1r[j] = ws[WS_W1F + j * 64 + lane];

  float v_out = 0.f, o_sum = 0.f;  // wave0, lane<11

  const float* xbase = x + (size_t)b * T_STEPS * 2048;
  const float* w2b  = ws + WS_W2F;
  const float* fc1T = ws + WS_FC1T;

  float4 xpre;
  if (tid < 512) xpre = ((const float4*)xbase)[tid];   // prefetch t=0

  __syncthreads();

  for (int t = 0; t < T_STEPS; ++t) {
    // ---- phase 1: commit prefetched x_t to XT (ic-stride 1040: odd-ic lanes
    //      land 16 banks away from even-ic -> conflict-free conv1 row reads) ----
    if (tid < 512) {
      int pl = tid >> 8;
      *(float4*)&sm[pl * 1040 + ((tid & 255) << 2)] = xpre;
    }
    __syncthreads();                                     // barrier A
    if (tid < 512) {
      int tn = (t + 1 < T_STEPS) ? t + 1 : t;
      xpre = ((const float4*)(xbase + tn * 2048))[tid];  // prefetch t+1
    }

    // ---- phase 2: conv1 + BN + LIF; rows 0-11 -> waves 0-11; 12,13 -> 10,11 ----
    for (int rr = 0; rr < 2; ++rr) {
      int py = (rr == 0) ? wave : ((wave == 10) ? 12 : (wave == 11) ? 13 : -1);
      if (py >= 0) {
        float acc[14];
        #pragma unroll
        for (int p = 0; p < 14; ++p) acc[p] = 0.f;
        const float* xr = &sm[ic1 * 1040 + py * 64];
        #pragma unroll
        for (int r = 0; r < 6; ++r) {
          float row[32];
          const float4* rp = (const float4*)&xr[r * 32];
          #pragma unroll
          for (int q = 0; q < 8; ++q) {
            float4 f = rp[q];
            row[4*q] = f.x; row[4*q+1] = f.y; row[4*q+2] = f.z; row[4*q+3] = f.w;
          }
          #pragma unroll
          for (int v = 0; v < 6; ++v) {
            float wv = w1r[r * 6 + v];
            #pragma unroll
            for (int px = 0; px < 14; ++px) acc[px] += row[2*px + v] * wv;
          }
        }
        #pragma unroll
        for (int px = 0; px < 14; ++px) acc[px] += __shfl_xor(acc[px], 1);
        if (ic1 == 0) {
          float flag = 0.f;
          #pragma unroll
          for (int px = 0; px < 14; ++px) {
            float c = acc[px] * s1v + sh1v;
            const int vidx = L_VC1 + (py * 14 + px) * 32 + oc1;
            float vold = sm[vidx];
            float v = b1v * vold + (1.f - b1v) * c;
            float s = (v > 1.f) ? 1.f : 0.f;
            sm[vidx] = v * (1.f - s);
            sm[L_SPK1 + oc1 * 228 + py * 16 + px] = s;
            flag += s;
          }
          sm[L_FLAG + oc1 * 14 + py] = flag;
        }
      }
    }
    if (tid == 0) *cntI = 0;
    __syncthreads();                                     // barrier B

    // ---- phase 3: conv2, 12-way (g = ic-group of 8, hh = u-pair band).
    //      Each wave: 8 planes x 10 rows x 30 fmac -- perfectly balanced.
    //      Per row exactly one py: py = u0>>1, tap row jb = (u0&1)*6. ----
    {
      const int g = wave & 3, hh = wave >> 2;
      float acc[25];
      #pragma unroll
      for (int p = 0; p < 25; ++p) acc[p] = 0.f;
      for (int kk = 0; kk < 8; ++kk) {
        const int ic = g + 4 * kk;
        const float* fl = &sm[L_FLAG + ic * 14 + 2 * hh];
        float flg[10]; float fsum = 0.f;
        #pragma unroll
        for (int u0 = 0; u0 < 10; ++u0) { flg[u0] = fl[u0]; fsum += flg[u0]; }
        if (fsum != 0.f) {               // skip dead plane-bands
          float w[12];
          {
            const float4* wp = ((const float4*)w2b) + (ic * 3 + hh) * 3 * 64 + lane;
            #pragma unroll
            for (int q = 0; q < 3; ++q) {
              float4 f = wp[q * 64];
              w[4*q] = f.x; w[4*q+1] = f.y; w[4*q+2] = f.z; w[4*q+3] = f.w;
            }
          }
          const float* srow = &sm[L_SPK1 + ic * 228 + 2 * hh * 16];
          #pragma unroll
          for (int u0 = 0; u0 < 10; ++u0) {
            if (flg[u0] != 0.f) {        // wave-uniform; exact (row all zero)
              float row[16];
              const float4* rp = (const float4*)&srow[u0 * 16];
              #pragma unroll
              for (int q = 0; q < 4; ++q) {
                float4 f = rp[q];
                row[4*q] = f.x; row[4*q+1] = f.y; row[4*q+2] = f.z; row[4*q+3] = f.w;
              }
              const int py = u0 >> 1;
              const int jb = (u0 & 1) * 6;
              #pragma unroll
              for (int v = 0; v < 6; ++v) {
                float wv = w[jb + v];
                #pragma unroll
                for (int px = 0; px < 5; ++px) acc[py * 5 + px] += row[2*px + v] * wv;
              }
            }
          }
        }
      }
      float* rb = (wave < 8) ? &sm[L_RED + wave * 1600] : &sm[L_P + (wave - 8) * 1600];
      #pragma unroll
      for (int p = 0; p < 25; ++p) rb[lane * 25 + p] = acc[p];
    }
    __syncthreads();                                     // barrier C

    // ---- phase 4: reduce 12 buffers + BN + LIF -> spike list ----
    {
      #pragma unroll
      for (int k = 0; k < 3; ++k) {
        int n = tid + NT * k;
        float s = 0.f;
        if (n < 1600) {
          float ssum = 0.f;
          #pragma unroll
          for (int w0 = 0; w0 < 8; ++w0) ssum += sm[L_RED + w0 * 1600 + n];
          #pragma unroll
          for (int w1 = 0; w1 < 4; ++w1) ssum += sm[L_P + w1 * 1600 + n];
          int oc = n / 25;
          float c2 = ssum * sm[L_BN2 + oc] + sm[L_BN2 + 64 + oc];
          float b2 = sm[L_BN2 + 128 + oc];
          const int vidx = L_VC2 + n;
          float vold = sm[vidx];
          float v = b2 * vold + (1.f - b2) * c2;
          s = (v > 1.f) ? 1.f : 0.f;
          sm[vidx] = v * (1.f - s);
        }
        unsigned long long mask = __ballot(s > 0.f);
        if (mask) {
          int base = 0;
          if (lane == 0) base = atomicAdd(cntI, __popcll(mask));
          base = __shfl(base, 0);
          if (s > 0.f) {
            int pos = __popcll(mask & ((1ull << lane) - 1ull));
            listI[base + pos] = n;
          }
        }
      }
    }
    __syncthreads();                                     // barrier D

    // ---- phase 5: fc1 = sparse gather, float4/lane, 12-way split, 4 accs ----
    {
      const int nn = *cntI;
      const float4* fc4 = (const float4*)fc1T;
      float4 a0 = {0.f,0.f,0.f,0.f}, a1 = {0.f,0.f,0.f,0.f};
      float4 a2 = {0.f,0.f,0.f,0.f}, a3 = {0.f,0.f,0.f,0.f};
      int i = wave;
      for (; i + 36 < nn; i += 48) {
        int k0 = listI[i], k1 = listI[i + 12], k2 = listI[i + 24], k3 = listI[i + 36];
        float4 f0 = fc4[k0 * 64 + lane];
        float4 f1 = fc4[k1 * 64 + lane];
        float4 f2 = fc4[k2 * 64 + lane];
        float4 f3 = fc4[k3 * 64 + lane];
        a0.x += f0.x; a0.y += f0.y; a0.z += f0.z; a0.w += f0.w;
        a1.x += f1.x; a1.y += f1.y; a1.z += f1.z; a1.w += f1.w;
        a2.x += f2.x; a2.y += f2.y; a2.z += f2.z; a2.w += f2.w;
        a3.x += f3.x; a3.y += f3.y; a3.z += f3.z; a3.w += f3.w;
      }
      for (; i < nn; i += 12) {
        int k = listI[i];
        float4 f = fc4[k * 64 + lane];
        a0.x += f.x; a0.y += f.y; a0.z += f.z; a0.w += f.w;
      }
      a0.x += a1.x + a2.x + a3.x;
      a0.y += a1.y + a2.y + a3.y;
      a0.z += a1.z + a2.z + a3.z;
      a0.w += a1.w + a2.w + a3.w;
      ((float4*)&sm[L_IPART2])[wave * 64 + lane] = a0;   // aliases RED[0..3072)
    }
    __syncthreads();                                     // barrier E

    // ---- phases 6-8 (wave 0 only): fc adaptive LIF, fc_out (L2), integrator ----
    // No trailing barrier: all waves wait at next barrier A until wave 0 arrives.
    if (wave == 0) {
      float sk[4];
      #pragma unroll
      for (int k = 0; k < 4; ++k) {
        int j = lane + 64 * k;
        float I = 0.f;
        #pragma unroll
        for (int h2 = 0; h2 < 12; ++h2) I += sm[L_IPART2 + h2 * 256 + j];
        float al = sm[L_FCP + j], rh = sm[L_FCP + 256 + j], ba = sm[L_FCP + 512 + j];
        float vf = sm[L_FCS + j], af = sm[L_FCS + 256 + j], sp0 = sm[L_FCS + 512 + j];
        af = rh * af + (1.f - rh) * sp0;
        float v = al * vf + (1.f - al) * I;
        float sp = (v > 1.f + ba * af) ? 1.f : 0.f;
        sm[L_FCS + j] = v * (1.f - sp);
        sm[L_FCS + 256 + j] = af;
        sm[L_FCS + 512 + j] = sp;
        sk[k] = sp;
      }
      const float4* wop = ((const float4*)(ws + WS_WOUTP)) + lane;
      float p[11];
      #pragma unroll
      for (int o = 0; o < 11; ++o) {
        float4 f = wop[o * 64];          // coalesced, L2-hot (11 KB total)
        p[o] = sk[0] * f.x + sk[1] * f.y + sk[2] * f.z + sk[3] * f.w;
      }
      #pragma unroll
      for (int m = 1; m < 64; m <<= 1)
        #pragma unroll
        for (int o = 0; o < 11; ++o) p[o] += __shfl_xor(p[o], m);
      float Isel = p[0];
      #pragma unroll
      for (int o = 1; o < 11; ++o) Isel = (lane == o) ? p[o] : Isel;
      if (lane < 11) {
        v_out = beta_o * v_out + (1.f - beta_o) * Isel;
        o_sum += v_out;
      }
    }
  }

  if (wave == 0 && lane < 11) out[b * 11 + lane] = o_sum * (1.f / T_STEPS);
}

extern "C" void kernel_launch(void* const* d_in, const int* in_sizes, int n_in,
                              void* d_out, int out_size, void* d_ws, size_t ws_size,
                              hipStream_t stream) {
  const float* x            = (const float*)d_in[0];
  const float* conv1_w      = (const float*)d_in[1];
  const float* bn1_gamma    = (const float*)d_in[2];
  const float* bn1_beta     = (const float*)d_in[3];
  const float* bn1_mean     = (const float*)d_in[4];
  const float* bn1_var      = (const float*)d_in[5];
  const float* conv2_w      = (const float*)d_in[6];
  const float* bn2_gamma    = (const float*)d_in[7];
  const float* bn2_beta     = (const float*)d_in[8];
  const float* bn2_mean     = (const float*)d_in[9];
  const float* bn2_var      = (const float*)d_in[10];
  const float* beta_c1_raw  = (const float*)d_in[11];
  const float* beta_c2_raw  = (const float*)d_in[12];
  const float* fc1_w        = (const float*)d_in[13];
  const float* alpha_raw    = (const float*)d_in[14];
  const float* rho_raw      = (const float*)d_in[15];
  const float* beta_a_p     = (const float*)d_in[16];
  const float* fc_out_w     = (const float*)d_in[17];
  const float* beta_out_p   = (const float*)d_in[18];
  float* ws  = (float*)d_ws;
  float* outp = (float*)d_out;

  (void)in_sizes; (void)n_in; (void)out_size; (void)ws_size;

  hipFuncSetAttribute((const void*)snn_kernel,
                      hipFuncAttributeMaxDynamicSharedMemorySize, SMEM_BYTES);

  prep_kernel<<<dim3((WS_TOTAL + 255) / 256), dim3(256), 0, stream>>>(
      conv1_w, conv2_w, fc1_w, fc_out_w, ws);

  snn_kernel<<<dim3(128), dim3(NT), SMEM_BYTES, stream>>>(
      x, bn1_gamma, bn1_beta, bn1_mean, bn1_var,
      bn2_gamma, bn2_beta, bn2_mean, bn2_var,
      beta_c1_raw, beta_c2_raw, alpha_raw, rho_raw, beta_a_p,
      fc_out_w, beta_out_p, ws, outp);
}

// Round 7
// 833.489 us; speedup vs baseline: 2.5346x; 1.0355x over previous
//
#include <hip/hip_runtime.h>
#include <math.h>

#define T_STEPS 50
#define NT 768

// workspace layout (float offsets)
#define WS_FC1T 0          // 1600*256 = 409600 : fc1_w transposed [k][j]
#define WS_W2F  409600     // 32*9*64*4 = 73728 : folded conv2, tap-quad-major [ic][q][oc][4]
#define WS_W1F  483328     // 36*64 = 2304 : folded conv1 [j][oc*2+ic]
#define WS_WOUTP 485632    // 2816 : fc_out packed [(o*64+lane)*4+k] = fc_out[o*256+k*64+lane]
#define WS_TOTAL 488448

// LDS layout (float offsets).
// IPART2 aliases RED[0..3072): RED is written in phase 3 (barrier B..C) and read
// in phase 4 (..barrier D); IPART2 is written in phase 5 (D..E) and read by
// wave 0 in phase 6. Next step's RED writes happen only after barrier B, which
// wave 0 reaches only after finishing phase 6 -> no overlap.
#define L_XT    0          // 2080 : x_t tile, ic-stride 1040 (bank-conflict fix)
#define L_SPK1  2080       // 7296 : 32 planes, stride 228
#define L_RED   9376       // 12800 : 8 conv2 partial buffers
#define L_IPART2 L_RED     // 3072 alias : fc1 partials, 12 waves x 256
#define L_LIST  22176      // 1600 (ints)
#define L_FLAG  23776      // 448
#define L_CNT   24224      // 16
#define L_VC1   24240      // 6272 : conv1 membrane, [py*14+px]*32 + oc
#define L_VC2   30512      // 1600
#define L_BN2   32112      // 192 : s2 | sh2 | b2
#define L_FCP   32304      // 768 : alpha | rho | beta_a
#define L_FCS   33072      // 768 : vfc | afc | spf
#define L_TOTALF 33840     // 135360 B -> 1 WG/CU (needs >80KB), well under 160 KiB
#define SMEM_BYTES (L_TOTALF * 4)

__global__ void prep_kernel(const float* __restrict__ conv1_w,
                            const float* __restrict__ conv2_w,
                            const float* __restrict__ fc1_w,
                            const float* __restrict__ fc_out_w,
                            float* __restrict__ ws) {
  int i = blockIdx.x * blockDim.x + threadIdx.x;
  if (i < 409600) {
    int k = i >> 8, j = i & 255;
    ws[WS_FC1T + i] = fc1_w[j * 1600 + k];
  } else if (i < 483328) {
    // tap-quad-major: i2 = ((ic*9 + q)*64 + oc)*4 + r, tap jj = 4q + r
    int i2 = i - 409600;
    int r  = i2 & 3;
    int t2 = i2 >> 2;
    int oc = t2 & 63;
    int t3 = t2 >> 6;      // ic*9 + q
    int q  = t3 % 9;
    int ic = t3 / 9;
    int jj = q * 4 + r, u = jj / 6, v = jj % 6;
    float s = 0.f;
    for (int dy = 0; dy < 2; ++dy) {
      int ky = u - dy; if (ky < 0 || ky > 4) continue;
      for (int dx = 0; dx < 2; ++dx) {
        int kx = v - dx; if (kx < 0 || kx > 4) continue;
        s += conv2_w[((oc * 32 + ic) * 5 + ky) * 5 + kx];
      }
    }
    ws[WS_W2F + i2] = 0.25f * s;
  } else if (i < 485632) {
    int i3 = i - 483328;
    int jj = i3 >> 6, l = i3 & 63, oc = l >> 1, ic = l & 1, u = jj / 6, v = jj % 6;
    float s = 0.f;
    for (int dy = 0; dy < 2; ++dy) {
      int ky = u - dy; if (ky < 0 || ky > 4) continue;
      for (int dx = 0; dx < 2; ++dx) {
        int kx = v - dx; if (kx < 0 || kx > 4) continue;
        s += conv1_w[((oc * 2 + ic) * 5 + ky) * 5 + kx];
      }
    }
    ws[WS_W1F + i3] = 0.25f * s;
  } else if (i < WS_TOTAL) {
    // fc_out packed for per-lane float4 loads in phase 6
    int i4 = i - 485632;
    int k  = i4 & 3;
    int s_ = i4 >> 2;
    int ln = s_ & 63;
    int o  = s_ >> 6;
    ws[WS_WOUTP + i4] = fc_out_w[o * 256 + k * 64 + ln];
  }
}

// block = 768 (12 waves), LDS 135KB -> 1 WG/CU = 3 waves/SIMD, VGPR budget 128.
// Phase 3 uses ONLY 8 waves with the read-minimal conv2 body: each live spike
// row is read ONCE per ic (448 dense row-visits) and reused for all 5 py.
// Round-5's 12-way u-band split read each row up to 3x (960 visits) -- the LDS
// data path is per-CU (shared by all SIMDs), so that duplication throttled the
// whole step; waves 8-11 idling here costs nothing (VALU work is conserved).
__global__ __launch_bounds__(NT, 2) void snn_kernel(
    const float* __restrict__ x,
    const float* __restrict__ bn1_gamma, const float* __restrict__ bn1_beta,
    const float* __restrict__ bn1_mean,  const float* __restrict__ bn1_var,
    const float* __restrict__ bn2_gamma, const float* __restrict__ bn2_beta,
    const float* __restrict__ bn2_mean,  const float* __restrict__ bn2_var,
    const float* __restrict__ beta_c1_raw, const float* __restrict__ beta_c2_raw,
    const float* __restrict__ alpha_raw, const float* __restrict__ rho_raw,
    const float* __restrict__ beta_a_p,  const float* __restrict__ fc_out_w,
    const float* __restrict__ beta_out_p,
    const float* __restrict__ ws, float* __restrict__ out)
{
  extern __shared__ float sm[];
  int* listI = (int*)&sm[L_LIST];
  int* cntI  = (int*)&sm[L_CNT];
  const int tid = threadIdx.x, wave = tid >> 6, lane = tid & 63;
  const int b = blockIdx.x;

  // one-time state zero-init + param staging
  for (int i = tid; i < 6272; i += NT) sm[L_VC1 + i] = 0.f;
  for (int i = tid; i < 1600; i += NT) sm[L_VC2 + i] = 0.f;
  if (tid < 256) {
    sm[L_FCP + tid]       = 1.f / (1.f + expf(-alpha_raw[tid]));
    sm[L_FCP + 256 + tid] = 1.f / (1.f + expf(-rho_raw[tid]));
    sm[L_FCP + 512 + tid] = beta_a_p[tid];
    sm[L_FCS + tid] = 0.f;
    sm[L_FCS + 256 + tid] = 0.f;
    sm[L_FCS + 512 + tid] = 0.f;
  }
  if (tid < 64) {
    float s2 = bn2_gamma[tid] / sqrtf(bn2_var[tid] + 1e-5f);
    sm[L_BN2 + tid]       = s2;
    sm[L_BN2 + 64 + tid]  = bn2_beta[tid] - bn2_mean[tid] * s2;
    sm[L_BN2 + 128 + tid] = 1.f / (1.f + expf(-beta_c2_raw[tid]));
  }

  // conv1 lane mapping: lane = oc*2 + ic
  const int oc1 = lane >> 1, ic1 = lane & 1;
  const float s1v  = bn1_gamma[oc1] / sqrtf(bn1_var[oc1] + 1e-5f);
  const float sh1v = bn1_beta[oc1] - bn1_mean[oc1] * s1v;
  const float b1v  = 1.f / (1.f + expf(-beta_c1_raw[oc1]));
  const float beta_o = 1.f / (1.f + expf(-beta_out_p[0]));

  // conv1 weights: persistent in registers (36 regs)
  float w1r[36];
  #pragma unroll
  for (int j = 0; j < 36; ++j) w1r[j] = ws[WS_W1F + j * 64 + lane];

  float v_out = 0.f, o_sum = 0.f;  // wave0, lane<11

  const float* xbase = x + (size_t)b * T_STEPS * 2048;
  const float* w2f  = ws + WS_W2F;
  const float* fc1T = ws + WS_FC1T;

  float4 xpre;
  if (tid < 512) xpre = ((const float4*)xbase)[tid];   // prefetch t=0

  __syncthreads();

  for (int t = 0; t < T_STEPS; ++t) {
    // ---- phase 1: commit prefetched x_t to XT (ic-stride 1040) ----
    if (tid < 512) {
      int pl = tid >> 8;
      *(float4*)&sm[L_XT + pl * 1040 + ((tid & 255) << 2)] = xpre;
    }
    __syncthreads();                                     // barrier A
    if (tid < 512) {
      int tn = (t + 1 < T_STEPS) ? t + 1 : t;
      xpre = ((const float4*)(xbase + tn * 2048))[tid];  // prefetch t+1
    }

    // ---- phase 2: conv1 + BN + LIF; rows 0-11 -> waves 0-11; 12,13 -> 10,11 ----
    for (int rr = 0; rr < 2; ++rr) {
      int py = (rr == 0) ? wave : ((wave == 10) ? 12 : (wave == 11) ? 13 : -1);
      if (py >= 0) {
        float acc[14];
        #pragma unroll
        for (int p = 0; p < 14; ++p) acc[p] = 0.f;
        const float* xr = &sm[L_XT + ic1 * 1040 + py * 64];
        #pragma unroll
        for (int r = 0; r < 6; ++r) {
          float row[32];
          const float4* rp = (const float4*)&xr[r * 32];
          #pragma unroll
          for (int q = 0; q < 8; ++q) {
            float4 f = rp[q];
            row[4*q] = f.x; row[4*q+1] = f.y; row[4*q+2] = f.z; row[4*q+3] = f.w;
          }
          #pragma unroll
          for (int v = 0; v < 6; ++v) {
            float wv = w1r[r * 6 + v];
            #pragma unroll
            for (int px = 0; px < 14; ++px) acc[px] += row[2*px + v] * wv;
          }
        }
        #pragma unroll
        for (int px = 0; px < 14; ++px) acc[px] += __shfl_xor(acc[px], 1);
        if (ic1 == 0) {
          float flag = 0.f;
          #pragma unroll
          for (int px = 0; px < 14; ++px) {
            float c = acc[px] * s1v + sh1v;
            const int vidx = L_VC1 + (py * 14 + px) * 32 + oc1;
            float vold = sm[vidx];
            float v = b1v * vold + (1.f - b1v) * c;
            float s = (v > 1.f) ? 1.f : 0.f;
            sm[vidx] = v * (1.f - s);
            sm[L_SPK1 + oc1 * 228 + py * 16 + px] = s;
            flag += s;
          }
          sm[L_FLAG + oc1 * 14 + py] = flag;
        }
      }
    }
    if (tid == 0) *cntI = 0;
    __syncthreads();                                     // barrier B

    // ---- phase 3: conv2, read-minimal body on waves 0-7; lane=oc, 4 ic/wave ----
    if (wave < 8) {
      float acc[25];
      #pragma unroll
      for (int p = 0; p < 25; ++p) acc[p] = 0.f;
      for (int ib = 0; ib < 4; ++ib) {
        const int ic = wave + 8 * ib;
        const float* fl = &sm[L_FLAG + ic * 14];
        float flg[14]; float fsum = 0.f;
        #pragma unroll
        for (int iy = 0; iy < 14; ++iy) { flg[iy] = fl[iy]; fsum += flg[iy]; }
        if (fsum != 0.f) {               // skip dead input planes entirely
          float w[36];
          {
            const float4* wp = ((const float4*)w2f) + (ic * 9) * 64 + lane;
            #pragma unroll
            for (int q = 0; q < 9; ++q) {
              float4 f = wp[q * 64];
              w[4*q] = f.x; w[4*q+1] = f.y; w[4*q+2] = f.z; w[4*q+3] = f.w;
            }
          }
          const float* srow = &sm[L_SPK1 + ic * 228];
          #pragma unroll
          for (int iy = 0; iy < 14; ++iy) {
            if (flg[iy] != 0.f) {        // wave-uniform branch; exact (row all zero)
              float row[16];
              const float4* rp = (const float4*)&srow[iy * 16];
              #pragma unroll
              for (int q = 0; q < 4; ++q) {
                float4 f = rp[q];
                row[4*q] = f.x; row[4*q+1] = f.y; row[4*q+2] = f.z; row[4*q+3] = f.w;
              }
              #pragma unroll
              for (int py = 0; py < 5; ++py) {
                const int u = iy - 2 * py;
                if (u >= 0 && u <= 5) {
                  #pragma unroll
                  for (int v = 0; v < 6; ++v) {
                    float wv = w[u * 6 + v];
                    #pragma unroll
                    for (int px = 0; px < 5; ++px) acc[py * 5 + px] += row[2*px + v] * wv;
                  }
                }
              }
            }
          }
        }
      }
      #pragma unroll
      for (int p = 0; p < 25; ++p) sm[L_RED + wave * 1600 + lane * 25 + p] = acc[p];
    }
    __syncthreads();                                     // barrier C

    // ---- phase 4: reduce 8 buffers + BN + LIF -> spike list ----
    {
      #pragma unroll
      for (int k = 0; k < 3; ++k) {
        int n = tid + NT * k;
        float s = 0.f;
        if (n < 1600) {
          float ssum = 0.f;
          #pragma unroll
          for (int wv = 0; wv < 8; ++wv) ssum += sm[L_RED + wv * 1600 + n];
          int oc = n / 25;
          float c2 = ssum * sm[L_BN2 + oc] + sm[L_BN2 + 64 + oc];
          float b2 = sm[L_BN2 + 128 + oc];
          const int vidx = L_VC2 + n;
          float vold = sm[vidx];
          float v = b2 * vold + (1.f - b2) * c2;
          s = (v > 1.f) ? 1.f : 0.f;
          sm[vidx] = v * (1.f - s);
        }
        unsigned long long mask = __ballot(s > 0.f);
        if (mask) {
          int base = 0;
          if (lane == 0) base = atomicAdd(cntI, __popcll(mask));
          base = __shfl(base, 0);
          if (s > 0.f) {
            int pos = __popcll(mask & ((1ull << lane) - 1ull));
            listI[base + pos] = n;
          }
        }
      }
    }
    __syncthreads();                                     // barrier D

    // ---- phase 5: fc1 = sparse gather, float4/lane, 12-way split, 4 accs ----
    {
      const int nn = *cntI;
      const float4* fc4 = (const float4*)fc1T;
      float4 a0 = {0.f,0.f,0.f,0.f}, a1 = {0.f,0.f,0.f,0.f};
      float4 a2 = {0.f,0.f,0.f,0.f}, a3 = {0.f,0.f,0.f,0.f};
      int i = wave;
      for (; i + 36 < nn; i += 48) {
        int k0 = listI[i], k1 = listI[i + 12], k2 = listI[i + 24], k3 = listI[i + 36];
        float4 f0 = fc4[k0 * 64 + lane];
        float4 f1 = fc4[k1 * 64 + lane];
        float4 f2 = fc4[k2 * 64 + lane];
        float4 f3 = fc4[k3 * 64 + lane];
        a0.x += f0.x; a0.y += f0.y; a0.z += f0.z; a0.w += f0.w;
        a1.x += f1.x; a1.y += f1.y; a1.z += f1.z; a1.w += f1.w;
        a2.x += f2.x; a2.y += f2.y; a2.z += f2.z; a2.w += f2.w;
        a3.x += f3.x; a3.y += f3.y; a3.z += f3.z; a3.w += f3.w;
      }
      for (; i < nn; i += 12) {
        int k = listI[i];
        float4 f = fc4[k * 64 + lane];
        a0.x += f.x; a0.y += f.y; a0.z += f.z; a0.w += f.w;
      }
      a0.x += a1.x + a2.x + a3.x;
      a0.y += a1.y + a2.y + a3.y;
      a0.z += a1.z + a2.z + a3.z;
      a0.w += a1.w + a2.w + a3.w;
      ((float4*)&sm[L_IPART2])[wave * 64 + lane] = a0;   // aliases RED[0..3072)
    }
    __syncthreads();                                     // barrier E

    // ---- phases 6-8 (wave 0 only): fc adaptive LIF, fc_out (L2), integrator ----
    // No trailing barrier: all waves wait at next barrier A until wave 0 arrives,
    // so wave 0's IPART2 reads finish before any wave's next-step RED writes.
    if (wave == 0) {
      float sk[4];
      #pragma unroll
      for (int k = 0; k < 4; ++k) {
        int j = lane + 64 * k;
        float I = 0.f;
        #pragma unroll
        for (int h2 = 0; h2 < 12; ++h2) I += sm[L_IPART2 + h2 * 256 + j];
        float al = sm[L_FCP + j], rh = sm[L_FCP + 256 + j], ba = sm[L_FCP + 512 + j];
        float vf = sm[L_FCS + j], af = sm[L_FCS + 256 + j], sp0 = sm[L_FCS + 512 + j];
        af = rh * af + (1.f - rh) * sp0;
        float v = al * vf + (1.f - al) * I;
        float sp = (v > 1.f + ba * af) ? 1.f : 0.f;
        sm[L_FCS + j] = v * (1.f - sp);
        sm[L_FCS + 256 + j] = af;
        sm[L_FCS + 512 + j] = sp;
        sk[k] = sp;
      }
      const float4* wop = ((const float4*)(ws + WS_WOUTP)) + lane;
      float p[11];
      #pragma unroll
      for (int o = 0; o < 11; ++o) {
        float4 f = wop[o * 64];          // coalesced, L2-hot (11 KB total)
        p[o] = sk[0] * f.x + sk[1] * f.y + sk[2] * f.z + sk[3] * f.w;
      }
      #pragma unroll
      for (int m = 1; m < 64; m <<= 1)
        #pragma unroll
        for (int o = 0; o < 11; ++o) p[o] += __shfl_xor(p[o], m);
      float Isel = p[0];
      #pragma unroll
      for (int o = 1; o < 11; ++o) Isel = (lane == o) ? p[o] : Isel;
      if (lane < 11) {
        v_out = beta_o * v_out + (1.f - beta_o) * Isel;
        o_sum += v_out;
      }
    }
  }

  if (wave == 0 && lane < 11) out[b * 11 + lane] = o_sum * (1.f / T_STEPS);
}

extern "C" void kernel_launch(void* const* d_in, const int* in_sizes, int n_in,
                              void* d_out, int out_size, void* d_ws, size_t ws_size,
                              hipStream_t stream) {
  const float* x            = (const float*)d_in[0];
  const float* conv1_w      = (const float*)d_in[1];
  const float* bn1_gamma    = (const float*)d_in[2];
  const float* bn1_beta     = (const float*)d_in[3];
  const float* bn1_mean     = (const float*)d_in[4];
  const float* bn1_var      = (const float*)d_in[5];
  const float* conv2_w      = (const float*)d_in[6];
  const float* bn2_gamma    = (const float*)d_in[7];
  const float* bn2_beta     = (const float*)d_in[8];
  const float* bn2_mean     = (const float*)d_in[9];
  const float* bn2_var      = (const float*)d_in[10];
  const float* beta_c1_raw  = (const float*)d_in[11];
  const float* beta_c2_raw  = (const float*)d_in[12];
  const float* fc1_w        = (const float*)d_in[13];
  const float* alpha_raw    = (const float*)d_in[14];
  const float* rho_raw      = (const float*)d_in[15];
  const float* beta_a_p     = (const float*)d_in[16];
  const float* fc_out_w     = (const float*)d_in[17];
  const float* beta_out_p   = (const float*)d_in[18];
  float* ws  = (float*)d_ws;
  float* outp = (float*)d_out;

  (void)in_sizes; (void)n_in; (void)out_size; (void)ws_size;

  hipFuncSetAttribute((const void*)snn_kernel,
                      hipFuncAttributeMaxDynamicSharedMemorySize, SMEM_BYTES);

  prep_kernel<<<dim3((WS_TOTAL + 255) / 256), dim3(256), 0, stream>>>(
      conv1_w, conv2_w, fc1_w, fc_out_w, ws);

  snn_kernel<<<dim3(128), dim3(NT), SMEM_BYTES, stream>>>(
      x, bn1_gamma, bn1_beta, bn1_mean, bn1_var,
      bn2_gamma, bn2_beta, bn2_mean, bn2_var,
      beta_c1_raw, beta_c2_raw, alpha_raw, rho_raw, beta_a_p,
      fc_out_w, beta_out_p, ws, outp);
}

// Round 8
// 733.523 us; speedup vs baseline: 2.8800x; 1.1363x over previous
//
#include <hip/hip_runtime.h>
#include <math.h>

#define T_STEPS 50
#define NT 768

// workspace layout (float offsets)
#define WS_FC1T 0          // 1600*256 = 409600 : fc1_w transposed [k][j]
#define WS_W2F  409600     // 32*9*64*4 = 73728 : folded conv2, tap-quad-major [ic][q][oc][4]
#define WS_W1F  483328     // 36*64 = 2304 : folded conv1 [j][oc*2+ic]
#define WS_WOUTP 485632    // 2816 : fc_out packed [(o*64+lane)*4+k] = fc_out[o*256+k*64+lane]
#define WS_TOTAL 488448

// LDS layout (float offsets). 40240 floats = 160960 B <= 163840 (160 KiB).
// IPART2 aliases RED[0..3072): RED written phase 3 (B..C), read phase 4 (..D);
// IPART2 written phase 5 (D..E), read by wave 0 at the TOP of the next step
// (before barrier B, i.e. before the next RED write). Safe by barrier ordering.
#define L_XT    0          // 2080 : x_t tile, ic-stride 1040 (bank-conflict fix)
#define L_SPK1  2080       // 7296 : 32 planes, stride 228 (228%32=4 -> write spread)
#define L_RED   9376       // 19200 : 12 conv2 partial buffers
#define L_IPART2 L_RED     // 3072 alias : fc1 partials, 12 waves x 256
#define L_LIST  28576      // 1600 (ints)
#define L_FLAG  30176      // 448
#define L_CNT   30624      // 16
#define L_VC1   30640      // 6272 : conv1 membrane, [py*14+px]*32 + oc
#define L_VC2   36912      // 1600
#define L_BN2   38512      // 192 : s2 | sh2 | b2
#define L_FCP   38704      // 768 : alpha | rho | beta_a
#define L_FCS   39472      // 768 : vfc | afc | spf
#define L_TOTALF 40240
#define SMEM_BYTES (L_TOTALF * 4)

__global__ void prep_kernel(const float* __restrict__ conv1_w,
                            const float* __restrict__ conv2_w,
                            const float* __restrict__ fc1_w,
                            const float* __restrict__ fc_out_w,
                            float* __restrict__ ws) {
  int i = blockIdx.x * blockDim.x + threadIdx.x;
  if (i < 409600) {
    int k = i >> 8, j = i & 255;
    ws[WS_FC1T + i] = fc1_w[j * 1600 + k];
  } else if (i < 483328) {
    // tap-quad-major: i2 = ((ic*9 + q)*64 + oc)*4 + r, tap jj = 4q + r
    int i2 = i - 409600;
    int r  = i2 & 3;
    int t2 = i2 >> 2;
    int oc = t2 & 63;
    int t3 = t2 >> 6;      // ic*9 + q
    int q  = t3 % 9;
    int ic = t3 / 9;
    int jj = q * 4 + r, u = jj / 6, v = jj % 6;
    float s = 0.f;
    for (int dy = 0; dy < 2; ++dy) {
      int ky = u - dy; if (ky < 0 || ky > 4) continue;
      for (int dx = 0; dx < 2; ++dx) {
        int kx = v - dx; if (kx < 0 || kx > 4) continue;
        s += conv2_w[((oc * 32 + ic) * 5 + ky) * 5 + kx];
      }
    }
    ws[WS_W2F + i2] = 0.25f * s;
  } else if (i < 485632) {
    int i3 = i - 483328;
    int jj = i3 >> 6, l = i3 & 63, oc = l >> 1, ic = l & 1, u = jj / 6, v = jj % 6;
    float s = 0.f;
    for (int dy = 0; dy < 2; ++dy) {
      int ky = u - dy; if (ky < 0 || ky > 4) continue;
      for (int dx = 0; dx < 2; ++dx) {
        int kx = v - dx; if (kx < 0 || kx > 4) continue;
        s += conv1_w[((oc * 2 + ic) * 5 + ky) * 5 + kx];
      }
    }
    ws[WS_W1F + i3] = 0.25f * s;
  } else if (i < WS_TOTAL) {
    // fc_out packed for per-lane float4 loads in phase 6
    int i4 = i - 485632;
    int k  = i4 & 3;
    int s_ = i4 >> 2;
    int ln = s_ & 63;
    int o  = s_ >> 6;
    ws[WS_WOUTP + i4] = fc_out_w[o * 256 + k * 64 + ln];
  }
}

// block = 768 (12 waves), LDS 160.9KB -> 1 WG/CU = 3 waves/SIMD, VGPR ~84.
// Pipeline (5 barriers/step, was 6):
//   step top : wave 0 runs PHASE 6 of step t-1 (hidden under conv1 on waves 1-11)
//   barrier B: conv1 results -> conv2 (ALL 12 waves, single-visit ic split)
//   barrier C: RED -> phase 4 reduce/LIF/list
//   barrier D: list -> phase 5 fc1 gather; ALSO commit x(t+1) to XT here
//              (XT is dead after conv1, so no barrier A is needed at step top)
//   barrier E: IPART2 + XT ready for next step
__global__ __launch_bounds__(NT, 2) void snn_kernel(
    const float* __restrict__ x,
    const float* __restrict__ bn1_gamma, const float* __restrict__ bn1_beta,
    const float* __restrict__ bn1_mean,  const float* __restrict__ bn1_var,
    const float* __restrict__ bn2_gamma, const float* __restrict__ bn2_beta,
    const float* __restrict__ bn2_mean,  const float* __restrict__ bn2_var,
    const float* __restrict__ beta_c1_raw, const float* __restrict__ beta_c2_raw,
    const float* __restrict__ alpha_raw, const float* __restrict__ rho_raw,
    const float* __restrict__ beta_a_p,  const float* __restrict__ fc_out_w,
    const float* __restrict__ beta_out_p,
    const float* __restrict__ ws, float* __restrict__ out)
{
  extern __shared__ float sm[];
  int* listI = (int*)&sm[L_LIST];
  int* cntI  = (int*)&sm[L_CNT];
  const int tid = threadIdx.x, wave = tid >> 6, lane = tid & 63;
  const int b = blockIdx.x;

  // one-time state zero-init + param staging
  for (int i = tid; i < 6272; i += NT) sm[L_VC1 + i] = 0.f;
  for (int i = tid; i < 1600; i += NT) sm[L_VC2 + i] = 0.f;
  if (tid < 256) {
    sm[L_FCP + tid]       = 1.f / (1.f + expf(-alpha_raw[tid]));
    sm[L_FCP + 256 + tid] = 1.f / (1.f + expf(-rho_raw[tid]));
    sm[L_FCP + 512 + tid] = beta_a_p[tid];
    sm[L_FCS + tid] = 0.f;
    sm[L_FCS + 256 + tid] = 0.f;
    sm[L_FCS + 512 + tid] = 0.f;
  }
  if (tid < 64) {
    float s2 = bn2_gamma[tid] / sqrtf(bn2_var[tid] + 1e-5f);
    sm[L_BN2 + tid]       = s2;
    sm[L_BN2 + 64 + tid]  = bn2_beta[tid] - bn2_mean[tid] * s2;
    sm[L_BN2 + 128 + tid] = 1.f / (1.f + expf(-beta_c2_raw[tid]));
  }

  // conv1 lane mapping: lane = oc*2 + ic
  const int oc1 = lane >> 1, ic1 = lane & 1;
  const float s1v  = bn1_gamma[oc1] / sqrtf(bn1_var[oc1] + 1e-5f);
  const float sh1v = bn1_beta[oc1] - bn1_mean[oc1] * s1v;
  const float b1v  = 1.f / (1.f + expf(-beta_c1_raw[oc1]));
  const float beta_o = 1.f / (1.f + expf(-beta_out_p[0]));

  // conv1 weights: persistent in registers (36 regs)
  float w1r[36];
  #pragma unroll
  for (int j = 0; j < 36; ++j) w1r[j] = ws[WS_W1F + j * 64 + lane];

  float v_out = 0.f, o_sum = 0.f;  // wave0, lane<11

  const float* xbase = x + (size_t)b * T_STEPS * 2048;
  const float* w2f  = ws + WS_W2F;
  const float* fc1T = ws + WS_FC1T;

  // prologue: load+commit x0, prefetch x1
  float4 xpre;
  if (tid < 512) {
    float4 x0 = ((const float4*)xbase)[tid];
    *(float4*)&sm[L_XT + (tid >> 8) * 1040 + ((tid & 255) << 2)] = x0;
    int tn = (T_STEPS > 1) ? 1 : 0;
    xpre = ((const float4*)(xbase + tn * 2048))[tid];
  }

  __syncthreads();

  for (int t = 0; t < T_STEPS; ++t) {
    // ---- phase 2 region: waves 1-11 conv1(t); wave 0 runs phase 6 of t-1 ----
    if (wave == 0) {
      if (t > 0) {
        float sk[4];
        #pragma unroll
        for (int k = 0; k < 4; ++k) {
          int j = lane + 64 * k;
          float I = 0.f;
          #pragma unroll
          for (int h2 = 0; h2 < 12; ++h2) I += sm[L_IPART2 + h2 * 256 + j];
          float al = sm[L_FCP + j], rh = sm[L_FCP + 256 + j], ba = sm[L_FCP + 512 + j];
          float vf = sm[L_FCS + j], af = sm[L_FCS + 256 + j], sp0 = sm[L_FCS + 512 + j];
          af = rh * af + (1.f - rh) * sp0;
          float v = al * vf + (1.f - al) * I;
          float sp = (v > 1.f + ba * af) ? 1.f : 0.f;
          sm[L_FCS + j] = v * (1.f - sp);
          sm[L_FCS + 256 + j] = af;
          sm[L_FCS + 512 + j] = sp;
          sk[k] = sp;
        }
        const float4* wop = ((const float4*)(ws + WS_WOUTP)) + lane;
        float p[11];
        #pragma unroll
        for (int o = 0; o < 11; ++o) {
          float4 f = wop[o * 64];          // coalesced, L2-hot
          p[o] = sk[0] * f.x + sk[1] * f.y + sk[2] * f.z + sk[3] * f.w;
        }
        #pragma unroll
        for (int m = 1; m < 64; m <<= 1)
          #pragma unroll
          for (int o = 0; o < 11; ++o) p[o] += __shfl_xor(p[o], m);
        float Isel = p[0];
        #pragma unroll
        for (int o = 1; o < 11; ++o) Isel = (lane == o) ? p[o] : Isel;
        if (lane < 11) {
          v_out = beta_o * v_out + (1.f - beta_o) * Isel;
          o_sum += v_out;
        }
      }
      if (lane == 0) *cntI = 0;
    } else {
      // conv1 rows: waves 1-11 -> rows 0-10; waves 9-11 also rows 11-13
      for (int rr = 0; rr < 2; ++rr) {
        int py = (rr == 0) ? (wave - 1) : ((wave >= 9) ? wave + 2 : -1);
        if (py >= 0) {
          float acc[14];
          #pragma unroll
          for (int p = 0; p < 14; ++p) acc[p] = 0.f;
          const float* xr = &sm[L_XT + ic1 * 1040 + py * 64];
          #pragma unroll
          for (int r = 0; r < 6; ++r) {
            float row[32];
            const float4* rp = (const float4*)&xr[r * 32];
            #pragma unroll
            for (int q = 0; q < 8; ++q) {
              float4 f = rp[q];
              row[4*q] = f.x; row[4*q+1] = f.y; row[4*q+2] = f.z; row[4*q+3] = f.w;
            }
            #pragma unroll
            for (int v = 0; v < 6; ++v) {
              float wv = w1r[r * 6 + v];
              #pragma unroll
              for (int px = 0; px < 14; ++px) acc[px] += row[2*px + v] * wv;
            }
          }
          #pragma unroll
          for (int px = 0; px < 14; ++px) acc[px] += __shfl_xor(acc[px], 1);
          if (ic1 == 0) {
            float flag = 0.f;
            #pragma unroll
            for (int px = 0; px < 14; ++px) {
              float c = acc[px] * s1v + sh1v;
              const int vidx = L_VC1 + (py * 14 + px) * 32 + oc1;
              float vold = sm[vidx];
              float v = b1v * vold + (1.f - b1v) * c;
              float s = (v > 1.f) ? 1.f : 0.f;
              sm[vidx] = v * (1.f - s);
              sm[L_SPK1 + oc1 * 228 + py * 16 + px] = s;
              flag += s;
            }
            sm[L_FLAG + oc1 * 14 + py] = flag;
          }
        }
      }
    }
    __syncthreads();                                     // barrier B

    // ---- phase 3: conv2 on ALL 12 waves, single-visit ic split:
    //      waves 0-7: ics {w, w+8, w+16}; waves 8-11: ics {w+16, w+20} ----
    {
      const int nic    = (wave < 8) ? 3 : 2;
      const int ic0    = (wave < 8) ? wave : (16 + wave);
      const int icstep = (wave < 8) ? 8 : 4;
      float acc[25];
      #pragma unroll
      for (int p = 0; p < 25; ++p) acc[p] = 0.f;
      for (int ib = 0; ib < nic; ++ib) {
        const int ic = ic0 + ib * icstep;
        const float* fl = &sm[L_FLAG + ic * 14];
        float flg[14]; float fsum = 0.f;
        #pragma unroll
        for (int iy = 0; iy < 14; ++iy) { flg[iy] = fl[iy]; fsum += flg[iy]; }
        if (fsum != 0.f) {               // skip dead input planes entirely
          float w[36];
          {
            const float4* wp = ((const float4*)w2f) + (ic * 9) * 64 + lane;
            #pragma unroll
            for (int q = 0; q < 9; ++q) {
              float4 f = wp[q * 64];
              w[4*q] = f.x; w[4*q+1] = f.y; w[4*q+2] = f.z; w[4*q+3] = f.w;
            }
          }
          const float* srow = &sm[L_SPK1 + ic * 228];
          #pragma unroll
          for (int iy = 0; iy < 14; ++iy) {
            if (flg[iy] != 0.f) {        // wave-uniform branch; exact (row all zero)
              float row[16];
              const float4* rp = (const float4*)&srow[iy * 16];
              #pragma unroll
              for (int q = 0; q < 4; ++q) {
                float4 f = rp[q];
                row[4*q] = f.x; row[4*q+1] = f.y; row[4*q+2] = f.z; row[4*q+3] = f.w;
              }
              #pragma unroll
              for (int py = 0; py < 5; ++py) {
                const int u = iy - 2 * py;
                if (u >= 0 && u <= 5) {
                  #pragma unroll
                  for (int v = 0; v < 6; ++v) {
                    float wv = w[u * 6 + v];
                    #pragma unroll
                    for (int px = 0; px < 5; ++px) acc[py * 5 + px] += row[2*px + v] * wv;
                  }
                }
              }
            }
          }
        }
      }
      #pragma unroll
      for (int p = 0; p < 25; ++p) sm[L_RED + wave * 1600 + lane * 25 + p] = acc[p];
    }
    __syncthreads();                                     // barrier C

    // ---- phase 4: reduce 12 buffers + BN + LIF -> spike list ----
    {
      #pragma unroll
      for (int k = 0; k < 3; ++k) {
        int n = tid + NT * k;
        float s = 0.f;
        if (n < 1600) {
          float ssum = 0.f;
          #pragma unroll
          for (int wv = 0; wv < 12; ++wv) ssum += sm[L_RED + wv * 1600 + n];
          int oc = n / 25;
          float c2 = ssum * sm[L_BN2 + oc] + sm[L_BN2 + 64 + oc];
          float b2 = sm[L_BN2 + 128 + oc];
          const int vidx = L_VC2 + n;
          float vold = sm[vidx];
          float v = b2 * vold + (1.f - b2) * c2;
          s = (v > 1.f) ? 1.f : 0.f;
          sm[vidx] = v * (1.f - s);
        }
        unsigned long long mask = __ballot(s > 0.f);
        if (mask) {
          int base = 0;
          if (lane == 0) base = atomicAdd(cntI, __popcll(mask));
          base = __shfl(base, 0);
          if (s > 0.f) {
            int pos = __popcll(mask & ((1ull << lane) - 1ull));
            listI[base + pos] = n;
          }
        }
      }
    }
    __syncthreads();                                     // barrier D

    // ---- phase 5: fc1 sparse gather (12-way, 4 accs) + XT(t+1) commit ----
    {
      // commit next step's x tile (XT dead since conv1) and issue t+2 prefetch
      if (tid < 512) {
        *(float4*)&sm[L_XT + (tid >> 8) * 1040 + ((tid & 255) << 2)] = xpre;
        int tn = (t + 2 < T_STEPS) ? t + 2 : T_STEPS - 1;
        xpre = ((const float4*)(xbase + tn * 2048))[tid];
      }
      const int nn = *cntI;
      const float4* fc4 = (const float4*)fc1T;
      float4 a0 = {0.f,0.f,0.f,0.f}, a1 = {0.f,0.f,0.f,0.f};
      float4 a2 = {0.f,0.f,0.f,0.f}, a3 = {0.f,0.f,0.f,0.f};
      int i = wave;
      for (; i + 36 < nn; i += 48) {
        int k0 = listI[i], k1 = listI[i + 12], k2 = listI[i + 24], k3 = listI[i + 36];
        float4 f0 = fc4[k0 * 64 + lane];
        float4 f1 = fc4[k1 * 64 + lane];
        float4 f2 = fc4[k2 * 64 + lane];
        float4 f3 = fc4[k3 * 64 + lane];
        a0.x += f0.x; a0.y += f0.y; a0.z += f0.z; a0.w += f0.w;
        a1.x += f1.x; a1.y += f1.y; a1.z += f1.z; a1.w += f1.w;
        a2.x += f2.x; a2.y += f2.y; a2.z += f2.z; a2.w += f2.w;
        a3.x += f3.x; a3.y += f3.y; a3.z += f3.z; a3.w += f3.w;
      }
      for (; i < nn; i += 12) {
        int k = listI[i];
        float4 f = fc4[k * 64 + lane];
        a0.x += f.x; a0.y += f.y; a0.z += f.z; a0.w += f.w;
      }
      a0.x += a1.x + a2.x + a3.x;
      a0.y += a1.y + a2.y + a3.y;
      a0.z += a1.z + a2.z + a3.z;
      a0.w += a1.w + a2.w + a3.w;
      ((float4*)&sm[L_IPART2])[wave * 64 + lane] = a0;   // aliases RED[0..3072)
    }
    __syncthreads();                                     // barrier E
    // phase 6 for this t runs at the top of the next iteration (wave 0),
    // overlapped with conv1 on waves 1-11.
  }

  // epilogue: phase 6 for t = T_STEPS-1
  if (wave == 0) {
    float sk[4];
    #pragma unroll
    for (int k = 0; k < 4; ++k) {
      int j = lane + 64 * k;
      float I = 0.f;
      #pragma unroll
      for (int h2 = 0; h2 < 12; ++h2) I += sm[L_IPART2 + h2 * 256 + j];
      float al = sm[L_FCP + j], rh = sm[L_FCP + 256 + j], ba = sm[L_FCP + 512 + j];
      float vf = sm[L_FCS + j], af = sm[L_FCS + 256 + j], sp0 = sm[L_FCS + 512 + j];
      af = rh * af + (1.f - rh) * sp0;
      float v = al * vf + (1.f - al) * I;
      float sp = (v > 1.f + ba * af) ? 1.f : 0.f;
      sk[k] = sp;
    }
    const float4* wop = ((const float4*)(ws + WS_WOUTP)) + lane;
    float p[11];
    #pragma unroll
    for (int o = 0; o < 11; ++o) {
      float4 f = wop[o * 64];
      p[o] = sk[0] * f.x + sk[1] * f.y + sk[2] * f.z + sk[3] * f.w;
    }
    #pragma unroll
    for (int m = 1; m < 64; m <<= 1)
      #pragma unroll
      for (int o = 0; o < 11; ++o) p[o] += __shfl_xor(p[o], m);
    float Isel = p[0];
    #pragma unroll
    for (int o = 1; o < 11; ++o) Isel = (lane == o) ? p[o] : Isel;
    if (lane < 11) {
      v_out = beta_o * v_out + (1.f - beta_o) * Isel;
      o_sum += v_out;
      out[b * 11 + lane] = o_sum * (1.f / T_STEPS);
    }
  }
}

extern "C" void kernel_launch(void* const* d_in, const int* in_sizes, int n_in,
                              void* d_out, int out_size, void* d_ws, size_t ws_size,
                              hipStream_t stream) {
  const float* x            = (const float*)d_in[0];
  const float* conv1_w      = (const float*)d_in[1];
  const float* bn1_gamma    = (const float*)d_in[2];
  const float* bn1_beta     = (const float*)d_in[3];
  const float* bn1_mean     = (const float*)d_in[4];
  const float* bn1_var      = (const float*)d_in[5];
  const float* conv2_w      = (const float*)d_in[6];
  const float* bn2_gamma    = (const float*)d_in[7];
  const float* bn2_beta     = (const float*)d_in[8];
  const float* bn2_mean     = (const float*)d_in[9];
  const float* bn2_var      = (const float*)d_in[10];
  const float* beta_c1_raw  = (const float*)d_in[11];
  const float* beta_c2_raw  = (const float*)d_in[12];
  const float* fc1_w        = (const float*)d_in[13];
  const float* alpha_raw    = (const float*)d_in[14];
  const float* rho_raw      = (const float*)d_in[15];
  const float* beta_a_p     = (const float*)d_in[16];
  const float* fc_out_w     = (const float*)d_in[17];
  const float* beta_out_p   = (const float*)d_in[18];
  float* ws  = (float*)d_ws;
  float* outp = (float*)d_out;

  (void)in_sizes; (void)n_in; (void)out_size; (void)ws_size;

  hipFuncSetAttribute((const void*)snn_kernel,
                      hipFuncAttributeMaxDynamicSharedMemorySize, SMEM_BYTES);

  prep_kernel<<<dim3((WS_TOTAL + 255) / 256), dim3(256), 0, stream>>>(
      conv1_w, conv2_w, fc1_w, fc_out_w, ws);

  snn_kernel<<<dim3(128), dim3(NT), SMEM_BYTES, stream>>>(
      x, bn1_gamma, bn1_beta, bn1_mean, bn1_var,
      bn2_gamma, bn2_beta, bn2_mean, bn2_var,
      beta_c1_raw, beta_c2_raw, alpha_raw, rho_raw, beta_a_p,
      fc_out_w, beta_out_p, ws, outp);
}